// Round 6
// baseline (727.375 us; speedup 1.0000x reference)
//
#include <hip/hip_runtime.h>

// Problem constants (match reference setup_inputs / module constants)
#define EPS_F      1e-4f
#define GRID_RES_F 0.01f
#define ATOL_F     0.01f
#define RTOL_F     1e-5f

static constexpr int V = 1200;
static constexpr int E = 4800;
static constexpr int S = V + E;      // 6000 filtration points
static constexpr int P = 2500;
static constexpr int R = 3;
static constexpr int PR = P * R;     // 7500

// Output layout (flat fp32, return order):
//   bars0: [0, 7500)   bars1: [7500, 15000)
//   G0: (R,P,2S) at 15000   G1: follows   Gc0: (R,P,2)   Gc1: follows
static constexpr size_t G0_BASE  = 15000ull;
static constexpr size_t G_ELEMS  = (size_t)R * P * 2 * S;   // 90,000,000
static constexpr size_t GC0_BASE = G0_BASE + 2 * G_ELEMS;   // 180,015,000

// ---------------------------------------------------------------------------
// Kernel 1: build filtration table AND copy bars0/bars1 to the output head
// (one dispatch replaces build + 2 hipMemcpyAsync — saves graph replays).
// Threads [0,S): filt[j]=(fx,fy,tolx,toly). [S,S+PR): bars0. [S+PR,S+2PR): bars1.
// ---------------------------------------------------------------------------
__global__ void build_filt_kernel(const float* __restrict__ f_v,
                                  const int*   __restrict__ edges,
                                  const float* __restrict__ bars0,
                                  const float* __restrict__ bars1,
                                  float4*      __restrict__ filt,
                                  float*       __restrict__ out) {
    int j = blockIdx.x * blockDim.x + threadIdx.x;
    if (j < S) {
        float fx, fy;
        if (j < V) {
            fx = f_v[2 * j];
            fy = f_v[2 * j + 1];
        } else {
            int e = j - V;
            int a = edges[2 * e];
            int b = edges[2 * e + 1];
            fx = __fadd_rn(fmaxf(f_v[2 * a],     f_v[2 * b]),     EPS_F);
            fy = __fadd_rn(fmaxf(f_v[2 * a + 1], f_v[2 * b + 1]), EPS_F);
        }
        // tol = ATOL + RTOL*|f| with NumPy per-op rounding (no fma contract).
        float tolx = __fadd_rn(ATOL_F, __fmul_rn(RTOL_F, fabsf(fx)));
        float toly = __fadd_rn(ATOL_F, __fmul_rn(RTOL_F, fabsf(fy)));
        filt[j] = make_float4(fx, fy, tolx, toly);
    } else if (j < S + PR) {
        out[j - S] = bars0[j - S];
    } else if (j < S + 2 * PR) {
        out[j - S] = bars1[j - S - PR];   // out[7500 + k] = bars1[k]
    }
}

// ---------------------------------------------------------------------------
// min_k |l[k] - f| ; comparing vs tol is bit-exact-equivalent to
// any_k(|l[k]-f| <= tol) — min/cmp involve no rounding. Subs keep ref rounding.
// (Field-proven: absmax 0.0 in rounds 4-5.)
// ---------------------------------------------------------------------------
__device__ __forceinline__ float mindist(const float* l, float f) {
    float a = fabsf(__fsub_rn(l[0], f));
    float b = fabsf(__fsub_rn(l[1], f));
    float c = fabsf(__fsub_rn(l[2], f));
    float d = fabsf(__fsub_rn(l[3], f));
    float e = fabsf(__fsub_rn(l[4], f));
    return fminf(fminf(fminf(a, b), fminf(c, d)), e);  // -> v_min3 pairs
}

__device__ __forceinline__ void cell(const float4& f, float psum,
                                     const float* lxs, const float* lys,
                                     float& vx, float& vy,
                                     int& aux, int& alx, int& auy, int& aly) {
    float fsum = __fadd_rn(f.x, f.y);
    bool ab = fsum > psum, be = fsum < psum;
    float sg = ab ? 1.0f : (be ? -1.0f : 0.0f);
    bool cx = (mindist(lxs, f.x) <= f.z) && (f.y <= lys[4]);
    bool cy = (mindist(lys, f.y) <= f.w) && (f.x <= lxs[4]);
    vx = cx ? sg : 0.0f;   // vx = ux - lx == condx ? (above - below) : 0
    vy = cy ? sg : 0.0f;
    aux |= (int)(cx && ab); alx |= (int)(cx && be);
    auy |= (int)(cy && ab); aly |= (int)(cy && be);
}

// ---------------------------------------------------------------------------
// Kernel 2: one block per (bar-set, r, p) row. Contiguous wave stores
// (2 cells/thread -> one float4 at byte 16*lane) + software prefetch of the
// next iteration's filt cells.
// ---------------------------------------------------------------------------
__global__ __launch_bounds__(256) void grad_kernel(
        const float4* __restrict__ filt,
        const float*  __restrict__ bars0,
        const float*  __restrict__ bars1,
        const float*  __restrict__ sample_pts,
        float*        __restrict__ d_out) {
    const int p = blockIdx.x;   // 0..P-1
    const int r = blockIdx.y;   // 0..R-1
    const int b = blockIdx.z;   // 0..1

    const float* bar = (b == 0) ? bars0 : bars1;
    const float px = sample_pts[2 * p];
    const float py = sample_pts[2 * p + 1];
    const float psum = __fadd_rn(px, py);
    const float s  = __fadd_rn(bar[p * R + r], GRID_RES_F);
    const float s2 = __fmul_rn(2.0f, s);   // exact (x2)

    float lxs[5], lys[5];
    lxs[0] = __fadd_rn(-s2, px); lxs[1] = __fadd_rn(-s, px); lxs[2] = px;
    lxs[3] = __fadd_rn( s, px);  lxs[4] = __fadd_rn(s2, px);
    lys[0] = __fadd_rn(-s2, py); lys[1] = __fadd_rn(-s, py); lys[2] = py;
    lys[3] = __fadd_rn( s, py);  lys[4] = __fadd_rn(s2, py);

    float* Grow = d_out + G0_BASE + (size_t)b * G_ELEMS
                        + ((size_t)(r * P + p)) * (2 * S);

    __shared__ int sh_flags[4];
    if (threadIdx.x < 4) sh_flags[threadIdx.x] = 0;
    __syncthreads();

    int aux = 0, alx = 0, auy = 0, aly = 0;

    // 2 cells/thread/iter -> contiguous 1KB wave stores; prefetch next iter.
    int j = threadIdx.x * 2;
    float4 a0, a1;
    if (j < S) { a0 = filt[j]; a1 = filt[j + 1]; }
    while (j < S) {
        const int jn = j + 512;
        float4 b0, b1;
        if (jn < S) { b0 = filt[jn]; b1 = filt[jn + 1]; }
        float4 o;
        cell(a0, psum, lxs, lys, o.x, o.y, aux, alx, auy, aly);
        cell(a1, psum, lxs, lys, o.z, o.w, aux, alx, auy, aly);
        *reinterpret_cast<float4*>(Grow + 2 * j) = o;
        a0 = b0; a1 = b1;
        j = jn;
    }

    // Row-wide any() flags: benign-race shared writes (all writers store 1).
    if (aux) sh_flags[0] = 1;
    if (alx) sh_flags[1] = 1;
    if (auy) sh_flags[2] = 1;
    if (aly) sh_flags[3] = 1;
    __syncthreads();

    if (threadIdx.x == 0) {
        float cx = sh_flags[0] ? -1.0f : (sh_flags[1] ? 1.0f : 0.0f);
        float cy = sh_flags[2] ? -1.0f : (sh_flags[3] ? 1.0f : 0.0f);
        size_t gc = GC0_BASE + (size_t)b * ((size_t)R * P * 2)
                             + ((size_t)(r * P + p)) * 2;
        d_out[gc]     = cx;
        d_out[gc + 1] = cy;
    }
}

// ---------------------------------------------------------------------------
extern "C" void kernel_launch(void* const* d_in, const int* in_sizes, int n_in,
                              void* d_out, int out_size, void* d_ws, size_t ws_size,
                              hipStream_t stream) {
    const float* f_v        = (const float*)d_in[0];
    const int*   edges      = (const int*)d_in[1];
    const float* bars0      = (const float*)d_in[2];
    const float* bars1      = (const float*)d_in[3];
    const float* sample_pts = (const float*)d_in[4];
    float* out = (float*)d_out;

    float4* filt = (float4*)d_ws;   // S * 16 B = 96 KB scratch

    // One dispatch: build filt + bars0/bars1 passthrough.
    const int total = S + 2 * PR;   // 21000
    build_filt_kernel<<<(total + 255) / 256, 256, 0, stream>>>(
        f_v, edges, bars0, bars1, filt, out);

    dim3 grid(P, R, 2);
    grad_kernel<<<grid, 256, 0, stream>>>(filt, bars0, bars1, sample_pts, out);
}